// Round 3
// baseline (836.022 us; speedup 1.0000x reference)
//
#include <hip/hip_runtime.h>

// Haar wavelet (single-level 2D DWT), fp32.
// Input  x:   (B=8, C=64, H=512, W=512)
// Output out: (B=8, 4*C=256, H/2=256, W/2=256), channel = 4*c + f, f in {ll,lh,hl,hh}
//
// Memory-bound: 512 MiB in + 512 MiB out -> HBM roofline ~170us @ 6.3 TB/s.
// Each thread: 8 input columns x 2 rows (4x float4 loads, 64B) ->
// 4 output pixels per filter (4x float4 stores, 64B). Fully coalesced.

__global__ void haar_dwt_kernel(const float* __restrict__ x,
                                float* __restrict__ out,
                                int total_quads) {
    // Geometry: W=512, H2=256, W2=256, quads-per-row Wq=64, C=64, B=8
    const int stride = gridDim.x * blockDim.x;
    for (int i = blockIdx.x * blockDim.x + threadIdx.x;
         i < total_quads; i += stride) {
        const int wq = i & 63;           // quad index along output W: w2 = 4*wq..4*wq+3
        int r = i >> 6;
        const int h2 = r & 255;          // output row
        r >>= 8;
        const int c = r & 63;            // input channel
        const int b = r >> 6;            // batch

        // Input rows 2*h2, 2*h2+1, columns 8*wq .. 8*wq+7
        const long long in_base =
            (((long long)(b * 64 + c) * 512) + 2 * h2) * 512 + 8 * wq;
        const float4 t0 = *reinterpret_cast<const float4*>(x + in_base);
        const float4 t1 = *reinterpret_cast<const float4*>(x + in_base + 4);
        const float4 b0 = *reinterpret_cast<const float4*>(x + in_base + 512);
        const float4 b1 = *reinterpret_cast<const float4*>(x + in_base + 516);

        // Per output pixel p: x00=top[2p], x01=top[2p+1], x10=bot[2p], x11=bot[2p+1]
        float4 ll, lh, hl, hh;
        // p=0: t0.x t0.y b0.x b0.y
        ll.x = 0.5f * ( t0.x + t0.y + b0.x + b0.y);
        lh.x = 0.5f * (-t0.x - t0.y + b0.x + b0.y);
        hl.x = 0.5f * (-t0.x + t0.y - b0.x + b0.y);
        hh.x = 0.5f * ( t0.x - t0.y - b0.x + b0.y);
        // p=1: t0.z t0.w b0.z b0.w
        ll.y = 0.5f * ( t0.z + t0.w + b0.z + b0.w);
        lh.y = 0.5f * (-t0.z - t0.w + b0.z + b0.w);
        hl.y = 0.5f * (-t0.z + t0.w - b0.z + b0.w);
        hh.y = 0.5f * ( t0.z - t0.w - b0.z + b0.w);
        // p=2: t1.x t1.y b1.x b1.y
        ll.z = 0.5f * ( t1.x + t1.y + b1.x + b1.y);
        lh.z = 0.5f * (-t1.x - t1.y + b1.x + b1.y);
        hl.z = 0.5f * (-t1.x + t1.y - b1.x + b1.y);
        hh.z = 0.5f * ( t1.x - t1.y - b1.x + b1.y);
        // p=3: t1.z t1.w b1.z b1.w
        ll.w = 0.5f * ( t1.z + t1.w + b1.z + b1.w);
        lh.w = 0.5f * (-t1.z - t1.w + b1.z + b1.w);
        hl.w = 0.5f * (-t1.z + t1.w - b1.z + b1.w);
        hh.w = 0.5f * ( t1.z - t1.w - b1.z + b1.w);

        // Output: out[b][4*c + f][h2][4*wq .. 4*wq+3]
        const long long ch_stride = 256LL * 256LL;
        const long long out_base =
            (((long long)(b * 256 + c * 4) * 256) + h2) * 256 + 4 * wq;
        *reinterpret_cast<float4*>(out + out_base)                 = ll;
        *reinterpret_cast<float4*>(out + out_base + ch_stride)     = lh;
        *reinterpret_cast<float4*>(out + out_base + 2 * ch_stride) = hl;
        *reinterpret_cast<float4*>(out + out_base + 3 * ch_stride) = hh;
    }
}

extern "C" void kernel_launch(void* const* d_in, const int* in_sizes, int n_in,
                              void* d_out, int out_size, void* d_ws, size_t ws_size,
                              hipStream_t stream) {
    const float* x = (const float*)d_in[0];
    float* out = (float*)d_out;

    // total quads = B*C*H2*(W2/4) = 8*64*256*64 = 8,388,608
    const int total_quads = 8 * 64 * 256 * 64;
    const int block = 256;
    const int grid = 2048;  // grid-stride; 256 CU x 8 blocks/CU
    haar_dwt_kernel<<<grid, block, 0, stream>>>(x, out, total_quads);
}

// Round 5
// 821.813 us; speedup vs baseline: 1.0173x; 1.0173x over previous
//
#include <hip/hip_runtime.h>

// Haar wavelet (single-level 2D DWT), fp32.
// Input  x:   (B=8, C=64, H=512, W=512)
// Output out: (B=8, 4*C=256, H/2=256, W/2=256), channel = 4*c + f, f in {ll,lh,hl,hh}
//
// Memory-bound: 512 MiB in + 512 MiB out -> HBM roofline ~170us @ 6.3 TB/s
// (harness poison fills add ~690us to dur_us; kernel share <344us per rocprof r3).
// Each thread: 8 input cols x 2 rows (4x float4 loads, 64B) -> 4 output pixels
// per filter (4x float4 nontemporal stores; each wave-store = 1KiB contiguous row).

typedef float v4 __attribute__((ext_vector_type(4)));

__global__ __launch_bounds__(256) void haar_dwt_kernel(const float* __restrict__ x,
                                                       float* __restrict__ out) {
    // Geometry: W=512, H2=256, W2=256, quads-per-row Wq=64, C=64, B=8
    const int total_quads = 8 * 64 * 256 * 64;   // 8,388,608 = 2048*256*16 exactly
    const int stride = gridDim.x * blockDim.x;
    for (int i = blockIdx.x * blockDim.x + threadIdx.x;
         i < total_quads; i += stride) {
        const int wq = i & 63;           // quad index along output W: w2 = 4*wq..4*wq+3
        const int h2 = (i >> 6) & 255;   // output row
        const int bc = i >> 14;          // b*64 + c  (fused: out ch base = 4*bc)

        // Input rows 2*h2, 2*h2+1, columns 8*wq .. 8*wq+7
        const long long in_base =
            ((long long)bc * 512 + 2 * h2) * 512 + 8 * wq;
        const v4 t0 = __builtin_nontemporal_load((const v4*)(x + in_base));
        const v4 t1 = __builtin_nontemporal_load((const v4*)(x + in_base + 4));
        const v4 b0 = __builtin_nontemporal_load((const v4*)(x + in_base + 512));
        const v4 b1 = __builtin_nontemporal_load((const v4*)(x + in_base + 516));

        // Per output pixel p: x00=top[2p], x01=top[2p+1], x10=bot[2p], x11=bot[2p+1]
        v4 ll, lh, hl, hh;
        ll[0] = 0.5f * ( t0[0] + t0[1] + b0[0] + b0[1]);
        lh[0] = 0.5f * (-t0[0] - t0[1] + b0[0] + b0[1]);
        hl[0] = 0.5f * (-t0[0] + t0[1] - b0[0] + b0[1]);
        hh[0] = 0.5f * ( t0[0] - t0[1] - b0[0] + b0[1]);

        ll[1] = 0.5f * ( t0[2] + t0[3] + b0[2] + b0[3]);
        lh[1] = 0.5f * (-t0[2] - t0[3] + b0[2] + b0[3]);
        hl[1] = 0.5f * (-t0[2] + t0[3] - b0[2] + b0[3]);
        hh[1] = 0.5f * ( t0[2] - t0[3] - b0[2] + b0[3]);

        ll[2] = 0.5f * ( t1[0] + t1[1] + b1[0] + b1[1]);
        lh[2] = 0.5f * (-t1[0] - t1[1] + b1[0] + b1[1]);
        hl[2] = 0.5f * (-t1[0] + t1[1] - b1[0] + b1[1]);
        hh[2] = 0.5f * ( t1[0] - t1[1] - b1[0] + b1[1]);

        ll[3] = 0.5f * ( t1[2] + t1[3] + b1[2] + b1[3]);
        lh[3] = 0.5f * (-t1[2] - t1[3] + b1[2] + b1[3]);
        hl[3] = 0.5f * (-t1[2] + t1[3] - b1[2] + b1[3]);
        hh[3] = 0.5f * ( t1[2] - t1[3] - b1[2] + b1[3]);

        // Output: channel base 4*bc, +f; row h2; cols 4*wq..4*wq+3
        const long long ch_stride = 256LL * 256LL;
        const long long out_base =
            ((long long)(4 * bc) * 256 + h2) * 256 + 4 * wq;
        __builtin_nontemporal_store(ll, (v4*)(out + out_base));
        __builtin_nontemporal_store(lh, (v4*)(out + out_base + ch_stride));
        __builtin_nontemporal_store(hl, (v4*)(out + out_base + 2 * ch_stride));
        __builtin_nontemporal_store(hh, (v4*)(out + out_base + 3 * ch_stride));
    }
}

extern "C" void kernel_launch(void* const* d_in, const int* in_sizes, int n_in,
                              void* d_out, int out_size, void* d_ws, size_t ws_size,
                              hipStream_t stream) {
    const float* x = (const float*)d_in[0];
    float* out = (float*)d_out;
    const int block = 256;
    const int grid = 2048;  // 256 CU x 8 blocks/CU; 16 iters/thread, no tail
    haar_dwt_kernel<<<grid, block, 0, stream>>>(x, out);
}